// Round 6
// baseline (136.572 us; speedup 1.0000x reference)
//
#include <hip/hip_runtime.h>
#include <math.h>

// Problem constants
#define NUM_CLASSES 80
#define BBOX_ATTRS  85          // 5 + NUM_CLASSES
#define NA          3           // anchors
#define LH          76
#define LW          76
#define HW          5776        // 76*76
#define BATCH       16
#define TT          50          // targets per batch
#define NCELLS      (BATCH*NA*HW)     // 277248
#define PRED_BSTR   (NA*BBOX_ATTRS*HW) // 1472880 floats per batch
#define NSLOTS      (BATCH*TT)  // 800
#define BMW         542         // ceil(3*5776/32) bitmap words per batch
#define NB_A        271         // ceil(277248 / 1024) float4 conf blocks
#define NB_C        200         // 800 slot-waves / 4 waves per block
#define NBLK        (NB_A + BATCH + NB_C)   // 487

// Semantics (validated absmax 0.0 across R2-R5): harness ref is a NUMPY port;
// negative fancy indices WRAP (jnp mode='drop' lost):
//  - invalid GT rows scatter to (b, a=0, j=0, i=75): phantom positive cell,
//    tx=ty=0, tw=th=log(1e-16), class 0
//  - noobj a_d=-1 wraps to anchor 2: (2, gj, gi) zeroed whenever cond=false
// Scatter: last write wins for tx/ty/tw/th (winner = max t per cell);
// mask/tcls constant-1.0 sets -> union.
//
// R3: contended same-line atomics = 11 ns each -> per-block partials.
// R4: encode is on-chip-cheap -> recompute per consumer wave, no round-trip.
// R5: only ~8 us of 124.7 is ours; this round fuses the finalize dispatch
// into main via last-block-done (threadfence release + atomic counter +
// acquire; counter zeroed by a 4-byte hipMemsetAsync graph node).

__device__ __forceinline__ float clip_log(float p) {
    return fmaxf(logf(p), -100.0f);
}
__device__ __forceinline__ float bce(float p, float t) {
    return -(t * clip_log(p) + (1.0f - t) * clip_log(1.0f - p));
}
__device__ __forceinline__ float sigmoidf(float v) {
    return 1.0f / (1.0f + expf(-v));
}
__device__ __forceinline__ float conf_term(float v) {   // -clip_log(1 - sigmoid(v))
    return -clip_log(1.0f - sigmoidf(v));
}
__device__ __forceinline__ float wave_reduce(float v) {
    #pragma unroll
    for (int off = 32; off; off >>= 1) v += __shfl_down(v, off);
    return v;
}

struct GtEnc {
    unsigned key;      // (bn<<16)|(gj<<8)|wi
    float tx, ty, tw, th;
    unsigned cid;
    int gi, gj;
    int za[NA];        // noobj-zeroed anchor per a (numpy wrap)
};

__device__ __forceinline__ GtEnc encode_gt(const float* __restrict__ annot,
                                           int b, int t) {
    // scaled anchors = ANCHORS / 8 (exact in fp32)
    const float aw[NA] = {14.5f, 19.5f, 46.625f};
    const float ah[NA] = {11.25f, 24.75f, 40.75f};
    GtEnc e;
    const float* an = annot + (b * TT + t) * 5;
    const float c0 = an[0], ax = an[1], ay = an[2], awd = an[3], aht = an[4];
    const bool valid = (c0 + ax + ay + awd + aht) != 0.0f;
    const float gx = ax * (float)LW, gy = ay * (float)LH;
    const float gw = awd * (float)LW, gh = aht * (float)LH;
    e.gi = (int)floorf(gx); e.gj = (int)floorf(gy);
    float ious[NA];
    float best = -1.0f; int bn = 0;
    #pragma unroll
    for (int a = 0; a < NA; ++a) {
        const float inter = fminf(gw, aw[a]) * fminf(gh, ah[a]);
        const float uni = gw * (gh + 1e-9f) + aw[a] * (ah[a] + 1e-9f) - inter + 1e-9f;
        ious[a] = inter / uni;
        if (ious[a] > best) { best = ious[a]; bn = a; }  // argmax, first max
    }
    #pragma unroll
    for (int a = 0; a < NA; ++a)
        e.za[a] = (valid && ious[a] > 0.5f) ? a : (NA - 1);  // wrap -1 -> 2
    e.tx = gx - floorf(gx);
    e.ty = gy - floorf(gy);
    e.tw = logf(gw / aw[bn] + 1e-16f);
    e.th = logf(gh / ah[bn] + 1e-16f);
    const int wi = valid ? e.gi : (LW - 1);   // numpy wrap of -1
    e.key = ((unsigned)bn << 16) | ((unsigned)e.gj << 8) | (unsigned)wi;
    e.cid = (unsigned)(int)c0;                // 0 for invalid rows
    return e;
}

// ---------------------------------------------------------------------------
// Single fused kernel. Block roles:
//   [0, NB_A)            : conf sum, float4 x 256 threads -> conf_partial[blk]
//   [NB_A, NB_A+16)      : in-LDS encode bitmap + noobj conf -> noobj_partial[b]
//   [NB_A+16, +16+NB_C)  : 4 slot-waves/block; per-wave register encode ->
//                          8-float record per slot (plain stores)
// Tail (all blocks): fence-release + done-counter; last block acquires and
// runs the final reduction, writing out[0]. NO early returns anywhere.
// ---------------------------------------------------------------------------
__global__ void __launch_bounds__(256)
main_kernel(const float* __restrict__ pred,
            const float* __restrict__ annot,
            float* __restrict__ conf_partial,
            float* __restrict__ noobj_partial,
            float4* __restrict__ rec,
            unsigned* __restrict__ done_counter,
            float* __restrict__ out) {
    __shared__ float smem[4];
    __shared__ unsigned bm[BMW];
    __shared__ bool sLast;
    const int blk = blockIdx.x;
    const int tid = threadIdx.x;
    const int lane = tid & 63;
    const int wave = tid >> 6;

    if (blk < NB_A) {
        // ---- conf sum over all cells, float4 (plane 5776 % 4 == 0: no straddle)
        const int c = (blk * 256 + tid) * 4;
        float v = 0.0f;
        if (c < NCELLS) {
            const int b = c / (NA * HW);
            const int rem = c - b * (NA * HW);
            const int a = rem / HW;
            const int r2 = rem - a * HW;
            const float4 p4 = *(const float4*)(pred + (size_t)b * PRED_BSTR
                                + (size_t)(a * BBOX_ATTRS + 4) * HW + r2);
            v = conf_term(p4.x) + conf_term(p4.y) + conf_term(p4.z) + conf_term(p4.w);
        }
        v = wave_reduce(v);
        if (lane == 0) smem[wave] = v;
        __syncthreads();
        if (tid == 0)
            conf_partial[blk] = smem[0] + smem[1] + smem[2] + smem[3];
    } else if (blk < NB_A + BATCH) {
        // ---- per-batch: build noobj bitmap in LDS, then subtract-sum it
        const int b = blk - NB_A;
        for (int w = tid; w < BMW; w += 256) bm[w] = 0u;
        __syncthreads();
        if (tid < TT) {
            const GtEnc e = encode_gt(annot, b, tid);
            #pragma unroll
            for (int a = 0; a < NA; ++a) {
                const int idx = e.za[a] * HW + e.gj * LW + e.gi;
                atomicOr(&bm[idx >> 5], 1u << (idx & 31));
            }
        }
        __syncthreads();
        float v = 0.0f;
        for (int w = tid; w < BMW; w += 256) {
            unsigned m = bm[w];
            while (m) {
                const int bit = __ffs(m) - 1;
                m &= m - 1u;
                const int idx = w * 32 + bit;
                const int a = idx / HW;
                const int r2 = idx - a * HW;
                v += conf_term(pred[(size_t)b * PRED_BSTR
                        + (size_t)(a * BBOX_ATTRS + 4) * HW + r2]);
            }
        }
        v = wave_reduce(v);
        if (lane == 0) smem[wave] = v;
        __syncthreads();
        if (tid == 0)
            noobj_partial[b] = smem[0] + smem[1] + smem[2] + smem[3];
    } else {
        // ---- one wave per slot; encode recomputed in-register via shuffles
        const int s = (blk - NB_A - BATCH) * 4 + wave;   // 0..799
        const int b = s / TT;
        const int t0 = s - b * TT;

        unsigned key = 0xFFFFFFFFu, cid = 0u;
        float tx = 0.f, ty = 0.f, tw = 0.f, th = 0.f;
        if (lane < TT) {
            const GtEnc e = encode_gt(annot, b, lane);
            key = e.key; cid = e.cid;
            tx = e.tx; ty = e.ty; tw = e.tw; th = e.th;
        }
        const unsigned key0 = __shfl(key, t0);
        const bool match = (lane < TT) && (key == key0);
        const unsigned long long mball = __ballot(match);
        const bool winner = ((mball >> (t0 + 1)) == 0ULL);  // wave-uniform

        if (winner) {
            // class union over GTs sharing the cell (OR-butterfly, whole wave)
            unsigned w0 = 0u, w1 = 0u, w2 = 0u;
            if (match) {
                if (cid < 32) w0 = 1u << cid;
                else if (cid < 64) w1 = 1u << (cid - 32);
                else w2 = 1u << (cid - 64);
            }
            #pragma unroll
            for (int off = 1; off < 64; off <<= 1) {
                w0 |= __shfl_xor(w0, off);
                w1 |= __shfl_xor(w1, off);
                w2 |= __shfl_xor(w2, off);
            }
            const float tx0 = __shfl(tx, t0), ty0 = __shfl(ty, t0);
            const float tw0 = __shfl(tw, t0), th0 = __shfl(th, t0);

            const int a = (key0 >> 16) & 0xff, j = (key0 >> 8) & 0xff, i = key0 & 0xff;
            const float* base = pred + (size_t)b * PRED_BSTR
                              + (size_t)a * BBOX_ATTRS * HW + j * LW + i;

            float cv = 0.0f;
            for (int c = lane; c < NUM_CLASSES; c += 64) {
                const float p = sigmoidf(base[(size_t)(5 + c) * HW]);
                const unsigned word = (c < 32) ? w0 : ((c < 64) ? w1 : w2);
                const float t = ((word >> (c & 31)) & 1u) ? 1.0f : 0.0f;
                cv += bce(p, t);
            }
            cv = wave_reduce(cv);
            if (lane == 0) {
                const float px = sigmoidf(base[0]);
                const float py = sigmoidf(base[HW]);
                const float w  = base[2 * HW];
                const float h  = base[3 * HW];
                const float pc = sigmoidf(base[4 * HW]);
                rec[2 * s] = make_float4(bce(px, tx0), bce(py, ty0),
                                         (w - tw0) * (w - tw0),
                                         (h - th0) * (h - th0));
                rec[2 * s + 1] = make_float4(-clip_log(pc), cv, 1.0f, 0.f);
            }
        } else if (lane == 0) {
            rec[2 * s]     = make_float4(0.f, 0.f, 0.f, 0.f);
            rec[2 * s + 1] = make_float4(0.f, 0.f, 0.f, 0.f);
        }
    }

    // ---- last-block-done tail (all blocks, all threads reach here) ----
    __syncthreads();
    if (tid == 0) {
        __threadfence();                       // release partial stores
        const unsigned old = atomicAdd(done_counter, 1u);
        sLast = (old == (unsigned)(NBLK - 1));
    }
    __syncthreads();
    if (!sLast) return;
    __threadfence();                           // acquire others' stores

    // ---- final reduction (reuses this block's 256 threads) ----
    __shared__ float red[4][8];
    __shared__ float rednp[4];
    float conf_all = 0.0f;
    for (int k = tid; k < NB_A; k += 256) conf_all += conf_partial[k];
    float conf_sub = (tid < BATCH) ? noobj_partial[tid] : 0.0f;

    float sx = 0.f, sy = 0.f, sw = 0.f, sh = 0.f, scp = 0.f, scl = 0.f, np = 0.f;
    for (int s = tid; s < NSLOTS; s += 256) {
        const float4 r0 = rec[2 * s];
        const float4 r1 = rec[2 * s + 1];
        sx += r0.x; sy += r0.y; sw += r0.z; sh += r0.w;
        scp += r1.x; scl += r1.y; np += r1.z;
    }
    float vals[8] = {conf_all, conf_sub, sx, sy, sw, sh, scp, scl};
    #pragma unroll
    for (int k = 0; k < 8; ++k) vals[k] = wave_reduce(vals[k]);
    float npr = wave_reduce(np);
    if (lane == 0) {
        #pragma unroll
        for (int k = 0; k < 8; ++k) red[wave][k] = vals[k];
        rednp[wave] = npr;
    }
    __syncthreads();
    if (tid == 0) {
        float acc[8];
        #pragma unroll
        for (int k = 0; k < 8; ++k)
            acc[k] = red[0][k] + red[1][k] + red[2][k] + red[3][k];
        const float npos = rednp[0] + rednp[1] + rednp[2] + rednp[3];
        const float N = (float)NCELLS;
        const float loss_x = acc[2] / N;
        const float loss_y = acc[3] / N;
        const float loss_w = acc[4] / N;
        const float loss_h = acc[5] / N;
        const float loss_conf = acc[6] / N + 0.5f * ((acc[0] - acc[1]) / N);
        const float loss_cls = acc[7] / (npos * (float)NUM_CLASSES);
        out[0] = 0.5f * loss_x + 0.5f * loss_y + 2.5f * loss_w + 2.5f * loss_h
               + 1.0f * loss_conf + 1.0f * loss_cls;
    }
}

extern "C" void kernel_launch(void* const* d_in, const int* in_sizes, int n_in,
                              void* d_out, int out_size, void* d_ws, size_t ws_size,
                              hipStream_t stream) {
    const float* pred  = (const float*)d_in[0];
    const float* annot = (const float*)d_in[1];
    float* out = (float*)d_out;

    // Workspace: conf_partial[271] pad->[272] | noobj_partial[16] | rec[1600 f4]
    // | done_counter (u32, 16B-aligned)
    float* conf_partial  = (float*)d_ws;
    float* noobj_partial = conf_partial + 272;
    float4* rec          = (float4*)(conf_partial + 288);   // 1152 B: 16B-aligned
    unsigned* done_ctr   = (unsigned*)(conf_partial + 288 + NSLOTS * 8);

    // Tiny memset node: zero the done-counter (async memset is capture-legal).
    hipMemsetAsync(done_ctr, 0, sizeof(unsigned), stream);

    main_kernel<<<NBLK, 256, 0, stream>>>(pred, annot, conf_partial,
                                          noobj_partial, rec, done_ctr, out);
}

// Round 7
// 125.197 us; speedup vs baseline: 1.0909x; 1.0909x over previous
//
#include <hip/hip_runtime.h>
#include <math.h>

// Problem constants
#define NUM_CLASSES 80
#define BBOX_ATTRS  85          // 5 + NUM_CLASSES
#define NA          3           // anchors
#define LH          76
#define LW          76
#define HW          5776        // 76*76
#define BATCH       16
#define TT          50          // targets per batch
#define NCELLS      (BATCH*NA*HW)     // 277248
#define PRED_BSTR   (NA*BBOX_ATTRS*HW) // 1472880 floats per batch
#define NSLOTS      (BATCH*TT)  // 800
#define BMW         542         // ceil(3*5776/32) bitmap words per batch
#define NB_A        271         // ceil(277248 / 1024) float4 conf blocks
#define NB_C        200         // 800 slot-waves / 4 waves per block

// Semantics (validated absmax 0.0 across R2-R6): harness ref is a NUMPY port;
// negative fancy indices WRAP (jnp mode='drop' lost):
//  - invalid GT rows scatter to (b, a=0, j=0, i=75): phantom positive cell,
//    tx=ty=0, tw=th=log(1e-16), class 0
//  - noobj a_d=-1 wraps to anchor 2: (2, gj, gi) zeroed whenever cond=false
// Scatter: last write wins for tx/ty/tw/th (winner = max t per cell);
// mask/tcls constant-1.0 sets -> union.
//
// R3: contended same-line atomics = 11 ns each -> per-block partials.
// R4: encode is on-chip-cheap -> recompute per consumer wave, no round-trip.
// R6 FAILED (+12 us): last-block-done fusion — 487 device-scope
// __threadfence (L2 wb/inv per block) + 487 contended atomics cost more
// than the 1-block finalize dispatch. REVERTED to R5 structure (124.7 us).

__device__ __forceinline__ float clip_log(float p) {
    return fmaxf(logf(p), -100.0f);
}
__device__ __forceinline__ float bce(float p, float t) {
    return -(t * clip_log(p) + (1.0f - t) * clip_log(1.0f - p));
}
__device__ __forceinline__ float sigmoidf(float v) {
    return 1.0f / (1.0f + expf(-v));
}
__device__ __forceinline__ float conf_term(float v) {   // -clip_log(1 - sigmoid(v))
    return -clip_log(1.0f - sigmoidf(v));
}
__device__ __forceinline__ float wave_reduce(float v) {
    #pragma unroll
    for (int off = 32; off; off >>= 1) v += __shfl_down(v, off);
    return v;
}

// Per-lane encode for GT row (b, t).
struct GtEnc {
    unsigned key;      // (bn<<16)|(gj<<8)|wi
    float tx, ty, tw, th;
    unsigned cid;
    int gi, gj;
    int za[NA];        // noobj-zeroed anchor per a (numpy wrap)
};

__device__ __forceinline__ GtEnc encode_gt(const float* __restrict__ annot,
                                           int b, int t) {
    // scaled anchors = ANCHORS / 8 (exact in fp32)
    const float aw[NA] = {14.5f, 19.5f, 46.625f};
    const float ah[NA] = {11.25f, 24.75f, 40.75f};
    GtEnc e;
    const float* an = annot + (b * TT + t) * 5;
    const float c0 = an[0], ax = an[1], ay = an[2], awd = an[3], aht = an[4];
    const bool valid = (c0 + ax + ay + awd + aht) != 0.0f;
    const float gx = ax * (float)LW, gy = ay * (float)LH;
    const float gw = awd * (float)LW, gh = aht * (float)LH;
    e.gi = (int)floorf(gx); e.gj = (int)floorf(gy);
    float ious[NA];
    float best = -1.0f; int bn = 0;
    #pragma unroll
    for (int a = 0; a < NA; ++a) {
        const float inter = fminf(gw, aw[a]) * fminf(gh, ah[a]);
        const float uni = gw * (gh + 1e-9f) + aw[a] * (ah[a] + 1e-9f) - inter + 1e-9f;
        ious[a] = inter / uni;
        if (ious[a] > best) { best = ious[a]; bn = a; }  // argmax, first max
    }
    #pragma unroll
    for (int a = 0; a < NA; ++a)
        e.za[a] = (valid && ious[a] > 0.5f) ? a : (NA - 1);  // wrap -1 -> 2
    e.tx = gx - floorf(gx);
    e.ty = gy - floorf(gy);
    e.tw = logf(gw / aw[bn] + 1e-16f);
    e.th = logf(gh / ah[bn] + 1e-16f);
    const int wi = valid ? e.gi : (LW - 1);   // numpy wrap of -1
    e.key = ((unsigned)bn << 16) | ((unsigned)e.gj << 8) | (unsigned)wi;
    e.cid = (unsigned)(int)c0;                // 0 for invalid rows
    return e;
}

// ---------------------------------------------------------------------------
// Single fused main kernel. Block roles:
//   [0, NB_A)            : conf sum, float4 x 256 threads -> conf_partial[blk]
//   [NB_A, NB_A+16)      : in-LDS encode bitmap + noobj conf -> noobj_partial[b]
//   [NB_A+16, +16+NB_C)  : 4 slot-waves/block; per-wave register encode ->
//                          8-float record per slot (plain stores)
// ---------------------------------------------------------------------------
__global__ void __launch_bounds__(256)
main_kernel(const float* __restrict__ pred,
            const float* __restrict__ annot,
            float* __restrict__ conf_partial,
            float* __restrict__ noobj_partial,
            float4* __restrict__ rec) {
    __shared__ float smem[4];
    __shared__ unsigned bm[BMW];
    const int blk = blockIdx.x;
    const int tid = threadIdx.x;
    const int lane = tid & 63;
    const int wave = tid >> 6;

    if (blk < NB_A) {
        // ---- conf sum over all cells, float4 (plane 5776 % 4 == 0: no straddle)
        const int c = (blk * 256 + tid) * 4;
        float v = 0.0f;
        if (c < NCELLS) {
            const int b = c / (NA * HW);
            const int rem = c - b * (NA * HW);
            const int a = rem / HW;
            const int r2 = rem - a * HW;
            const float4 p4 = *(const float4*)(pred + (size_t)b * PRED_BSTR
                                + (size_t)(a * BBOX_ATTRS + 4) * HW + r2);
            v = conf_term(p4.x) + conf_term(p4.y) + conf_term(p4.z) + conf_term(p4.w);
        }
        v = wave_reduce(v);
        if (lane == 0) smem[wave] = v;
        __syncthreads();
        if (tid == 0)
            conf_partial[blk] = smem[0] + smem[1] + smem[2] + smem[3];
    } else if (blk < NB_A + BATCH) {
        // ---- per-batch: build noobj bitmap in LDS, then subtract-sum it
        const int b = blk - NB_A;
        for (int w = tid; w < BMW; w += 256) bm[w] = 0u;
        __syncthreads();
        if (tid < TT) {
            const GtEnc e = encode_gt(annot, b, tid);
            #pragma unroll
            for (int a = 0; a < NA; ++a) {
                const int idx = e.za[a] * HW + e.gj * LW + e.gi;
                atomicOr(&bm[idx >> 5], 1u << (idx & 31));
            }
        }
        __syncthreads();
        float v = 0.0f;
        for (int w = tid; w < BMW; w += 256) {
            unsigned m = bm[w];
            while (m) {
                const int bit = __ffs(m) - 1;
                m &= m - 1u;
                const int idx = w * 32 + bit;
                const int a = idx / HW;
                const int r2 = idx - a * HW;
                v += conf_term(pred[(size_t)b * PRED_BSTR
                        + (size_t)(a * BBOX_ATTRS + 4) * HW + r2]);
            }
        }
        v = wave_reduce(v);
        if (lane == 0) smem[wave] = v;
        __syncthreads();
        if (tid == 0)
            noobj_partial[b] = smem[0] + smem[1] + smem[2] + smem[3];
    } else {
        // ---- one wave per slot; encode recomputed in-register via shuffles
        const int s = (blk - NB_A - BATCH) * 4 + wave;   // 0..799
        const int b = s / TT;
        const int t0 = s - b * TT;

        unsigned key = 0xFFFFFFFFu, cid = 0u;
        float tx = 0.f, ty = 0.f, tw = 0.f, th = 0.f;
        if (lane < TT) {
            const GtEnc e = encode_gt(annot, b, lane);
            key = e.key; cid = e.cid;
            tx = e.tx; ty = e.ty; tw = e.tw; th = e.th;
        }
        const unsigned key0 = __shfl(key, t0);
        const bool match = (lane < TT) && (key == key0);
        const unsigned long long mball = __ballot(match);
        const bool winner = ((mball >> (t0 + 1)) == 0ULL);  // no later t same cell

        if (!winner) {
            if (lane == 0) {
                rec[2 * s]     = make_float4(0.f, 0.f, 0.f, 0.f);
                rec[2 * s + 1] = make_float4(0.f, 0.f, 0.f, 0.f);
            }
            return;
        }
        // class union over all GTs sharing the cell (OR-butterfly, all lanes)
        unsigned w0 = 0u, w1 = 0u, w2 = 0u;
        if (match) {
            if (cid < 32) w0 = 1u << cid;
            else if (cid < 64) w1 = 1u << (cid - 32);
            else w2 = 1u << (cid - 64);
        }
        #pragma unroll
        for (int off = 1; off < 64; off <<= 1) {
            w0 |= __shfl_xor(w0, off);
            w1 |= __shfl_xor(w1, off);
            w2 |= __shfl_xor(w2, off);
        }
        const float tx0 = __shfl(tx, t0), ty0 = __shfl(ty, t0);
        const float tw0 = __shfl(tw, t0), th0 = __shfl(th, t0);

        const int a = (key0 >> 16) & 0xff, j = (key0 >> 8) & 0xff, i = key0 & 0xff;
        const float* base = pred + (size_t)b * PRED_BSTR
                          + (size_t)a * BBOX_ATTRS * HW + j * LW + i;

        float cv = 0.0f;
        for (int c = lane; c < NUM_CLASSES; c += 64) {
            const float p = sigmoidf(base[(size_t)(5 + c) * HW]);
            const unsigned word = (c < 32) ? w0 : ((c < 64) ? w1 : w2);
            const float t = ((word >> (c & 31)) & 1u) ? 1.0f : 0.0f;
            cv += bce(p, t);
        }
        cv = wave_reduce(cv);
        if (lane == 0) {
            const float px = sigmoidf(base[0]);
            const float py = sigmoidf(base[HW]);
            const float w  = base[2 * HW];
            const float h  = base[3 * HW];
            const float pc = sigmoidf(base[4 * HW]);
            rec[2 * s] = make_float4(bce(px, tx0), bce(py, ty0),
                                     (w - tw0) * (w - tw0),
                                     (h - th0) * (h - th0));
            rec[2 * s + 1] = make_float4(-clip_log(pc), cv, 1.0f, 0.f);
        }
    }
}

// ---------------------------------------------------------------------------
// Final reduction (1 block, 256 threads) — ~27 KB of partials
// ---------------------------------------------------------------------------
__global__ void __launch_bounds__(256)
finalize_kernel(const float* __restrict__ conf_partial,
                const float* __restrict__ noobj_partial,
                const float4* __restrict__ rec,
                float* __restrict__ out) {
    __shared__ float red[4][8];
    __shared__ float rednp[4];
    const int t = threadIdx.x;

    float conf_all = 0.0f;
    for (int k = t; k < NB_A; k += 256) conf_all += conf_partial[k];
    float conf_sub = (t < BATCH) ? noobj_partial[t] : 0.0f;

    float sx = 0.f, sy = 0.f, sw = 0.f, sh = 0.f, scp = 0.f, scl = 0.f, np = 0.f;
    for (int s = t; s < NSLOTS; s += 256) {
        const float4 r0 = rec[2 * s];
        const float4 r1 = rec[2 * s + 1];
        sx += r0.x; sy += r0.y; sw += r0.z; sh += r0.w;
        scp += r1.x; scl += r1.y; np += r1.z;
    }
    float vals[8] = {conf_all, conf_sub, sx, sy, sw, sh, scp, scl};
    #pragma unroll
    for (int k = 0; k < 8; ++k) vals[k] = wave_reduce(vals[k]);
    float npr = wave_reduce(np);
    const int wave = t >> 6;
    if ((t & 63) == 0) {
        #pragma unroll
        for (int k = 0; k < 8; ++k) red[wave][k] = vals[k];
        rednp[wave] = npr;
    }
    __syncthreads();
    if (t == 0) {
        float acc[8];
        #pragma unroll
        for (int k = 0; k < 8; ++k)
            acc[k] = red[0][k] + red[1][k] + red[2][k] + red[3][k];
        const float npos = rednp[0] + rednp[1] + rednp[2] + rednp[3];
        const float N = (float)NCELLS;
        const float loss_x = acc[2] / N;
        const float loss_y = acc[3] / N;
        const float loss_w = acc[4] / N;
        const float loss_h = acc[5] / N;
        const float loss_conf = acc[6] / N + 0.5f * ((acc[0] - acc[1]) / N);
        const float loss_cls = acc[7] / (npos * (float)NUM_CLASSES);
        out[0] = 0.5f * loss_x + 0.5f * loss_y + 2.5f * loss_w + 2.5f * loss_h
               + 1.0f * loss_conf + 1.0f * loss_cls;
    }
}

extern "C" void kernel_launch(void* const* d_in, const int* in_sizes, int n_in,
                              void* d_out, int out_size, void* d_ws, size_t ws_size,
                              hipStream_t stream) {
    const float* pred  = (const float*)d_in[0];
    const float* annot = (const float*)d_in[1];
    float* out = (float*)d_out;

    // Workspace: conf_partial[271] pad-> [272] | noobj_partial[16] | rec[1600 f4]
    float* conf_partial  = (float*)d_ws;
    float* noobj_partial = conf_partial + 272;
    float4* rec          = (float4*)(conf_partial + 288);   // 1152 B: 16B-aligned

    const int nblk = NB_A + BATCH + NB_C;  // 271 + 16 + 200 = 487
    main_kernel<<<nblk, 256, 0, stream>>>(pred, annot, conf_partial,
                                          noobj_partial, rec);

    finalize_kernel<<<1, 256, 0, stream>>>(conf_partial, noobj_partial, rec, out);
}